// Round 1
// baseline (1044.168 us; speedup 1.0000x reference)
//
#include <hip/hip_runtime.h>
#include <math.h>

// SGConv, fully fused single kernel — ZERO d_ws usage.
// Rationale: rocprof showed dur_us (84.5) == two 256MiB fillBufferAligned
// dispatches (42.4+42.3 us) == harness workspace re-poison. Our actual compute
// is ~10us. Fusing kA_build into k3 removes the inter-kernel M tensor and all
// workspace traffic.
//
// Per block: sigma via endpoint-mu power-squaring (as before), then exploit
// that D_a has only TWO distinct values (interior / boundary t in {0,127}):
// precompute D_int, D_bnd, D_int^2, D_bnd^2 in LDS, then each thread (tl,o)
// assembles its own M[t0+tl][dt][f][o] column straight into 80 registers.

#define MU_MIN (-1.99940694f)   // -2*cos(pi/129)

__device__ __forceinline__ float dot16(float x) {  // sum over lanes 0..15
  x += __shfl_xor(x, 1);
  x += __shfl_xor(x, 2);
  x += __shfl_xor(x, 4);
  x += __shfl_xor(x, 8);
  return x;
}

__global__ __launch_bounds__(256) void sgconv_fused(
    const float* __restrict__ x, const float* __restrict__ W,
    const float* __restrict__ bias, const float* __restrict__ adj,
    float* __restrict__ out) {
  const int tg = blockIdx.y, bg = blockIdx.x;
  const int t0 = tg * 16, b0 = bg * 16;
  const int tid = threadIdx.x;

  __shared__ float Bsh[256], Wsh[768];
  __shared__ float dis_i[16], dis_b[16], csh[1];
  __shared__ float H0[512], Pbuf[512], Qbuf[512];
  __shared__ float scl[2], lamsh[2];
  __shared__ int jst[2];
  __shared__ float Dint[256], Dbnd[256], DDint[256], DDbnd[256];
  __shared__ float xs[1600];  // 4 batches x 20 rows x (16+4 pad)

  // ---- load adj (sigmoid) + W ----
  {
    const int f = tid >> 4, g = tid & 15;
    const float a = adj[tid];
    const float s = 1.f / (1.f + expf(-a));
    Bsh[tid] = (f == g) ? 1.f : s;     // B = feat + self-loop (asymmetric)
    Wsh[tid] = W[tid];
    Wsh[tid + 256] = W[tid + 256];
    Wsh[tid + 512] = W[tid + 512];
  }
  __syncthreads();
  if (tid < 16) {
    float rsum = 0.f;
    for (int j = 0; j < 16; j++) rsum += Bsh[tid * 16 + j];  // row sums
    dis_i[tid] = 1.f / sqrtf(rsum + 2.f);  // interior t
    dis_b[tid] = 1.f / sqrtf(rsum + 1.f);  // t in {0,127}
  }
  __syncthreads();

  // ---- sigma: both endpoint-mu passes concurrently (thread halves) ----
  const int pass = tid >> 7, idx = tid & 127;
  const int pb = pass * 256;
  const float mu = pass ? -MU_MIN : MU_MIN;
  for (int e = idx; e < 256; e += 128) {
    const int f = e >> 4, g = e & 15;
    float gv = -dis_i[f] * Bsh[e] * dis_i[g];
    if (f == g) gv += 1.f - mu * dis_i[f] * dis_i[f];
    Pbuf[pb + e] = gv;
  }
  __syncthreads();
  for (int e = idx; e < 256; e += 128) {   // H0 = G^T G
    const int r = e >> 4, q = e & 15;
    float s = 0.f;
    #pragma unroll
    for (int k = 0; k < 16; k++) s += Pbuf[pb + k * 16 + r] * Pbuf[pb + k * 16 + q];
    H0[pb + e] = s;
    Qbuf[pb + e] = s;
  }
  __syncthreads();

  float* cur = Qbuf;
  float* nxt = Pbuf;
  #pragma unroll 1
  for (int it = 0; it < 8; it++) {   // cur -> cur^2 / trace^2  (H^256 total)
    if (idx == 0) {
      float tr = 0.f;
      #pragma unroll
      for (int d = 0; d < 16; d++) tr += cur[pb + d * 17];
      scl[pass] = 1.f / (tr * tr);
    }
    __syncthreads();
    const float s2 = scl[pass];
    for (int e = idx; e < 256; e += 128) {
      const int r = e >> 4, q = e & 15;
      const float4* rr = (const float4*)(cur + pb + r * 16);  // symmetric
      const float4* qq = (const float4*)(cur + pb + q * 16);
      float s = 0.f;
      #pragma unroll
      for (int k4 = 0; k4 < 4; k4++) {
        const float4 a = rr[k4], b = qq[k4];
        s += a.x * b.x + a.y * b.y + a.z * b.z + a.w * b.w;
      }
      nxt[pb + e] = s * s2;
    }
    __syncthreads();
    float* tmp = cur; cur = nxt; nxt = tmp;
  }
  if (idx == 0) {   // dominant column = argmax diagonal of H^256
    int bj = 0; float bd = -1.f;
    #pragma unroll
    for (int d = 0; d < 16; d++) {
      const float v = cur[pb + d * 17];
      if (v > bd) { bd = v; bj = d; }
    }
    jst[pass] = bj;
  }
  __syncthreads();
  if (idx < 16) {   // one-shot Rayleigh quotient against H0
    const int r = idx, js = jst[pass];
    const float vr = cur[pb + r * 16 + js];
    float hv = 0.f;
    #pragma unroll
    for (int q = 0; q < 16; q++) hv += H0[pb + r * 16 + q] * cur[pb + q * 16 + js];
    const float num = dot16(vr * hv);
    const float den = dot16(vr * vr);
    if (r == 0) lamsh[pass] = num / fmaxf(den, 1e-30f);
  }
  __syncthreads();
  if (tid == 0) {
    const float lam = fmaxf(fmaxf(lamsh[0], lamsh[1]), 1e-20f);
    csh[0] = 2.f / sqrtf(lam);   // c = 2 / sigma
  }
  __syncthreads();

  const float c = csh[0];
  // ---- the only two distinct D blocks + their squares ----
  {
    const int r = tid >> 4, q = tid & 15;
    const float di = (r == q) ? (c - 1.f) : 0.f;
    Dint[tid] = di - c * dis_i[r] * dis_i[q] * Bsh[tid];
    Dbnd[tid] = di - c * dis_b[r] * dis_b[q] * Bsh[tid];
  }
  __syncthreads();
  {
    const int r = tid >> 4, q = tid & 15;
    float s1 = 0.f, s2 = 0.f;
    #pragma unroll
    for (int k = 0; k < 16; k++) {
      s1 += Dint[r * 16 + k] * Dint[k * 16 + q];
      s2 += Dbnd[r * 16 + k] * Dbnd[k * 16 + q];
    }
    DDint[tid] = s1;
    DDbnd[tid] = s2;
  }
  __syncthreads();

  // ---- per-thread M column build: thread (tl,o) owns t=t0+tl, all f, all dt ----
  const int tl = tid >> 4, o = tid & 15;
  const int t = t0 + tl;
  const float* Dt   = (t == 0 || t == 127) ? Dbnd : Dint;
  const float* DDt  = (t == 0 || t == 127) ? DDbnd : DDint;
  const float* Dtp  = (t + 1 == 127) ? Dbnd : Dint;   // D_{t+1}; gated uses only
  const float* Dtm  = (t - 1 == 0) ? Dbnd : Dint;     // D_{t-1}; gated uses only
  const float* ut   = (t == 0 || t == 127) ? dis_b : dis_i;
  const float* utp  = (t + 1 >= 127) ? dis_b : dis_i;
  const float* utm  = (t - 1 <= 0) ? dis_b : dis_i;
  const float* utp2 = (t + 2 >= 127) ? dis_b : dis_i;
  const float* utm2 = (t - 2 <= 0) ? dis_b : dis_i;
  const float c2 = 2.f * c * c;

  float M[80];  // [dt][f] column for this (t,o) — constant-indexed (fully unrolled)
  #pragma unroll
  for (int f = 0; f < 16; f++) {
    const float utf = ut[f];
    const float utpf = utp[f], utmf = utm[f];
    const float gfp = -c * utpf * utf;
    const float gfm = -c * utmf * utf;
    const float w2f = Wsh[512 + f * 16 + o];
    float acc2 = Wsh[f * 16 + o];                 // dt = 0
    float acc3 = gfp * Wsh[256 + f * 16 + o];     // dt = +1
    float acc1 = gfm * Wsh[256 + f * 16 + o];     // dt = -1
    const float diag0 = c2 * utf * utf *
        ((t > 0 ? utmf * utmf : 0.f) + (t < 127 ? utpf * utpf : 0.f)) - 1.f;
    #pragma unroll
    for (int fp = 0; fp < 16; fp++) {
      const float w1 = Wsh[256 + fp * 16 + o];
      const float w2 = Wsh[512 + fp * 16 + o];
      const float d0 = Dt[f * 16 + fp];
      const float p2 = 2.f * DDt[f * 16 + fp] + ((f == fp) ? diag0 : 0.f);
      acc2 += d0 * w1 + p2 * w2;
      const float gqp = -c * utp[fp] * ut[fp];
      const float gqm = -c * utm[fp] * ut[fp];
      acc3 += 2.f * (gfp * d0 + Dtp[f * 16 + fp] * gqp) * w2;
      acc1 += 2.f * (Dtm[f * 16 + fp] * gqm + gfm * d0) * w2;
    }
    M[32 + f] = acc2;
    M[48 + f] = (t < 127) ? acc3 : 0.f;
    M[16 + f] = (t > 0) ? acc1 : 0.f;
    M[64 + f] = (t < 126) ? (c2 * utp2[f] * utpf * utpf * utf * w2f) : 0.f;  // dt=+2
    M[f]      = (t > 1)   ? (c2 * utm2[f] * utmf * utmf * utf * w2f) : 0.f;  // dt=-2
  }

  // ---- main loop: out[b,t,o] = bias + sum_{dt,f} x[b,t+dt-2,f] M[dt][f] ----
  const float bo = bias[o];
  for (int cc = 0; cc < 4; cc++) {
    __syncthreads();
    for (int i2 = tid; i2 < 320; i2 += 256) {
      const int cb = i2 / 80, rem = i2 % 80;
      const int rrow = rem >> 2, qq = rem & 3;
      int gr = t0 - 2 + rrow;
      gr = gr < 0 ? 0 : (gr > 127 ? 127 : gr);  // clamped rows hit M==0 entries
      const float4 v = *(const float4*)(x + ((size_t)(b0 + cc * 4 + cb) * 128 + gr) * 16 + qq * 4);
      *(float4*)(xs + cb * 400 + rrow * 20 + qq * 4) = v;
    }
    __syncthreads();
    #pragma unroll
    for (int cb = 0; cb < 4; cb++) {
      float acc0 = bo, acc1v = 0.f;
      #pragma unroll
      for (int dt = 0; dt < 5; dt++) {
        const float* xr = xs + cb * 400 + (tl + dt) * 20;
        const float4 xa = *(const float4*)(xr);
        const float4 xb = *(const float4*)(xr + 4);
        const float4 xc = *(const float4*)(xr + 8);
        const float4 xd = *(const float4*)(xr + 12);
        const float* Mp = M + dt * 16;
        acc0 += xa.x * Mp[0] + xa.y * Mp[1] + xa.z * Mp[2] + xa.w * Mp[3]
              + xb.x * Mp[4] + xb.y * Mp[5] + xb.z * Mp[6] + xb.w * Mp[7];
        acc1v += xc.x * Mp[8] + xc.y * Mp[9] + xc.z * Mp[10] + xc.w * Mp[11]
               + xd.x * Mp[12] + xd.y * Mp[13] + xd.z * Mp[14] + xd.w * Mp[15];
      }
      out[((size_t)(b0 + cc * 4 + cb) * 128 + t) * 16 + o] = acc0 + acc1v;
    }
  }
}

extern "C" void kernel_launch(void* const* d_in, const int* in_sizes, int n_in,
                              void* d_out, int out_size, void* d_ws, size_t ws_size,
                              hipStream_t stream) {
  const float* x    = (const float*)d_in[0];  // [1024,128,16]
  const float* W    = (const float*)d_in[1];  // [3,16,16]
  const float* bias = (const float*)d_in[2];  // [16]
  const float* adj  = (const float*)d_in[3];  // [16,16]
  (void)d_ws; (void)ws_size;                  // workspace deliberately UNUSED
  sgconv_fused<<<dim3(64, 8), dim3(256), 0, stream>>>(x, W, bias, adj, (float*)d_out);
}

// Round 3
// 95.428 us; speedup vs baseline: 10.9420x; 10.9420x over previous
//
#include <hip/hip_runtime.h>
#include <math.h>

// SGConv, fused single kernel, ZERO d_ws usage.
// R1 post-mortem: M[80] in registers across the unrolled build loop spilled
// (VGPR=256, 1.9GB scratch traffic, 1002us). Fix: build M into LDS, reload
// into registers after build pressure dies.
// R2 fix: Mlds[80][256] (80KB) was wasteful — M[t] depends on t only through
// boundary proximity; 7 equivalence classes {0},{1},{2},[3..124],{125},{126},
// {127}; any 16-row block touches <=4 -> Mlds[80][4][16] = 20KB. Total LDS
// ~41KB -> 2 blocks/CU at grid 512.

#define MU_MIN (-1.99940694f)   // -2*cos(pi/129)

__device__ __forceinline__ float dot16(float x) {  // sum over lanes 0..15
  x += __shfl_xor(x, 1);
  x += __shfl_xor(x, 2);
  x += __shfl_xor(x, 4);
  x += __shfl_xor(x, 8);
  return x;
}

__global__ __launch_bounds__(256) void sgconv_fused(
    const float* __restrict__ x, const float* __restrict__ W,
    const float* __restrict__ bias, const float* __restrict__ adj,
    float* __restrict__ out) {
  const int tg = blockIdx.y, bg = blockIdx.x;
  const int t0 = tg * 16, b0 = bg * 16;
  const int tid = threadIdx.x;

  __shared__ float Mlds[80 * 64];   // [k][cls<4][o] — 20KB
  __shared__ float Bsh[256], Wsh[768];
  __shared__ float dis_i[16], dis_b[16], csh[1];
  __shared__ float H0[512], Pbuf[512], Qbuf[512];
  __shared__ float scl[2], lamsh[2];
  __shared__ int jst[2];
  __shared__ float Dint[256], Dbnd[256], DDint[256], DDbnd[256];
  __shared__ float xs[1600];  // 4 batches x 20 rows x (16+4 pad)

  // ---- load adj (sigmoid) + W ----
  {
    const int f = tid >> 4, g = tid & 15;
    const float a = adj[tid];
    const float s = 1.f / (1.f + expf(-a));
    Bsh[tid] = (f == g) ? 1.f : s;     // B = feat + self-loop (asymmetric)
    Wsh[tid] = W[tid];
    Wsh[tid + 256] = W[tid + 256];
    Wsh[tid + 512] = W[tid + 512];
  }
  __syncthreads();
  if (tid < 16) {
    float rsum = 0.f;
    for (int j = 0; j < 16; j++) rsum += Bsh[tid * 16 + j];  // row sums
    dis_i[tid] = 1.f / sqrtf(rsum + 2.f);  // interior t
    dis_b[tid] = 1.f / sqrtf(rsum + 1.f);  // t in {0,127}
  }
  __syncthreads();

  // ---- sigma: both endpoint-mu passes concurrently (thread halves) ----
  const int pass = tid >> 7, idx = tid & 127;
  const int pb = pass * 256;
  const float mu = pass ? -MU_MIN : MU_MIN;
  for (int e = idx; e < 256; e += 128) {
    const int f = e >> 4, g = e & 15;
    float gv = -dis_i[f] * Bsh[e] * dis_i[g];
    if (f == g) gv += 1.f - mu * dis_i[f] * dis_i[f];
    Pbuf[pb + e] = gv;
  }
  __syncthreads();
  for (int e = idx; e < 256; e += 128) {   // H0 = G^T G
    const int r = e >> 4, q = e & 15;
    float s = 0.f;
    #pragma unroll
    for (int k = 0; k < 16; k++) s += Pbuf[pb + k * 16 + r] * Pbuf[pb + k * 16 + q];
    H0[pb + e] = s;
    Qbuf[pb + e] = s;
  }
  __syncthreads();

  float* cur = Qbuf;
  float* nxt = Pbuf;
  #pragma unroll 1
  for (int it = 0; it < 8; it++) {   // cur -> cur^2 / trace^2  (H^256 total)
    if (idx == 0) {
      float tr = 0.f;
      #pragma unroll
      for (int d = 0; d < 16; d++) tr += cur[pb + d * 17];
      scl[pass] = 1.f / (tr * tr);
    }
    __syncthreads();
    const float s2 = scl[pass];
    for (int e = idx; e < 256; e += 128) {
      const int r = e >> 4, q = e & 15;
      const float4* rr = (const float4*)(cur + pb + r * 16);  // symmetric
      const float4* qq = (const float4*)(cur + pb + q * 16);
      float s = 0.f;
      #pragma unroll
      for (int k4 = 0; k4 < 4; k4++) {
        const float4 a = rr[k4], b = qq[k4];
        s += a.x * b.x + a.y * b.y + a.z * b.z + a.w * b.w;
      }
      nxt[pb + e] = s * s2;
    }
    __syncthreads();
    float* tmp = cur; cur = nxt; nxt = tmp;
  }
  if (idx == 0) {   // dominant column = argmax diagonal of H^256
    int bj = 0; float bd = -1.f;
    #pragma unroll
    for (int d = 0; d < 16; d++) {
      const float v = cur[pb + d * 17];
      if (v > bd) { bd = v; bj = d; }
    }
    jst[pass] = bj;
  }
  __syncthreads();
  if (idx < 16) {   // one-shot Rayleigh quotient against H0
    const int r = idx, js = jst[pass];
    const float vr = cur[pb + r * 16 + js];
    float hv = 0.f;
    #pragma unroll
    for (int q = 0; q < 16; q++) hv += H0[pb + r * 16 + q] * cur[pb + q * 16 + js];
    const float num = dot16(vr * hv);
    const float den = dot16(vr * vr);
    if (r == 0) lamsh[pass] = num / fmaxf(den, 1e-30f);
  }
  __syncthreads();
  if (tid == 0) {
    const float lam = fmaxf(fmaxf(lamsh[0], lamsh[1]), 1e-20f);
    csh[0] = 2.f / sqrtf(lam);   // c = 2 / sigma
  }
  __syncthreads();

  const float c = csh[0];
  // ---- the only two distinct D blocks + their squares ----
  {
    const int r = tid >> 4, q = tid & 15;
    const float di = (r == q) ? (c - 1.f) : 0.f;
    Dint[tid] = di - c * dis_i[r] * dis_i[q] * Bsh[tid];
    Dbnd[tid] = di - c * dis_b[r] * dis_b[q] * Bsh[tid];
  }
  __syncthreads();
  {
    const int r = tid >> 4, q = tid & 15;
    float s1 = 0.f, s2 = 0.f;
    #pragma unroll
    for (int k = 0; k < 16; k++) {
      s1 += Dint[r * 16 + k] * Dint[k * 16 + q];
      s2 += Dbnd[r * 16 + k] * Dbnd[k * 16 + q];
    }
    DDint[tid] = s1;
    DDbnd[tid] = s2;
  }
  __syncthreads();

  // ---- build the <=4 distinct M classes this block needs (wave 0 only) ----
  const int tl = tid >> 4, o = tid & 15;
  if (tl < 4) {
    int t;  // representative t for class tl
    if (tg == 0)      t = (tl < 3) ? tl : 8;          // cls 0,1,2 = t=0,1,2; cls3 interior
    else if (tg == 7) t = (tl == 0) ? 112 : 124 + tl; // cls0 interior; cls1..3 = 125,126,127
    else              t = t0;                          // all-interior block
    const float* Dt   = (t == 0 || t == 127) ? Dbnd : Dint;
    const float* DDt  = (t == 0 || t == 127) ? DDbnd : DDint;
    const float* Dtp  = (t + 1 == 127) ? Dbnd : Dint;
    const float* Dtm  = (t - 1 == 0) ? Dbnd : Dint;
    const float* ut   = (t == 0 || t == 127) ? dis_b : dis_i;
    const float* utp  = (t + 1 >= 127) ? dis_b : dis_i;
    const float* utm  = (t - 1 <= 0) ? dis_b : dis_i;
    const float* utp2 = (t + 2 >= 127) ? dis_b : dis_i;
    const float* utm2 = (t - 2 <= 0) ? dis_b : dis_i;
    const float c2 = 2.f * c * c;

    for (int f = 0; f < 16; f++) {
      const float utf = ut[f];
      const float utpf = utp[f], utmf = utm[f];
      const float gfp = -c * utpf * utf;
      const float gfm = -c * utmf * utf;
      const float w2f = Wsh[512 + f * 16 + o];
      float acc2 = Wsh[f * 16 + o];                 // dt = 0
      float acc3 = gfp * Wsh[256 + f * 16 + o];     // dt = +1
      float acc1 = gfm * Wsh[256 + f * 16 + o];     // dt = -1
      const float diag0 = c2 * utf * utf *
          ((t > 0 ? utmf * utmf : 0.f) + (t < 127 ? utpf * utpf : 0.f)) - 1.f;
      #pragma unroll
      for (int fp = 0; fp < 16; fp++) {
        const float w1 = Wsh[256 + fp * 16 + o];
        const float w2 = Wsh[512 + fp * 16 + o];
        const float d0 = Dt[f * 16 + fp];
        const float p2 = 2.f * DDt[f * 16 + fp] + ((f == fp) ? diag0 : 0.f);
        acc2 += d0 * w1 + p2 * w2;
        const float gqp = -c * utp[fp] * ut[fp];
        const float gqm = -c * utm[fp] * ut[fp];
        acc3 += 2.f * (gfp * d0 + Dtp[f * 16 + fp] * gqp) * w2;
        acc1 += 2.f * (Dtm[f * 16 + fp] * gqm + gfm * d0) * w2;
      }
      const int col = tl * 16 + o;
      Mlds[(32 + f) * 64 + col] = acc2;
      Mlds[(48 + f) * 64 + col] = (t < 127) ? acc3 : 0.f;
      Mlds[(16 + f) * 64 + col] = (t > 0) ? acc1 : 0.f;
      Mlds[(64 + f) * 64 + col] =
          (t < 126) ? (c2 * utp2[f] * utpf * utpf * utf * w2f) : 0.f;  // dt=+2
      Mlds[f * 64 + col] =
          (t > 1) ? (c2 * utm2[f] * utmf * utmf * utf * w2f) : 0.f;    // dt=-2
    }
  }
  __syncthreads();

  // ---- reload own M column into registers (by class; broadcast reads) ----
  const int t = t0 + tl;
  int cls;
  if (tg == 0)      cls = (tl < 3) ? tl : 3;
  else if (tg == 7) cls = (tl <= 12) ? 0 : (tl - 12);
  else              cls = 0;
  float M[80];  // [dt][f]
  #pragma unroll
  for (int k = 0; k < 80; k++) M[k] = Mlds[k * 64 + cls * 16 + o];

  // ---- main loop: out[b,t,o] = bias + sum_{dt,f} x[b,t+dt-2,f] M[dt][f] ----
  const float bo = bias[o];
  float4 pf0, pf1;
  {  // prefetch cc = 0
    const int cb = tid / 80, rem = tid % 80;
    const int rrow = rem >> 2, qq = rem & 3;
    int gr = t0 - 2 + rrow;
    gr = gr < 0 ? 0 : (gr > 127 ? 127 : gr);
    pf0 = *(const float4*)(x + ((size_t)(b0 + cb) * 128 + gr) * 16 + qq * 4);
    if (tid < 64) {
      const int i2 = 256 + tid;
      const int cb1 = i2 / 80, rem1 = i2 % 80;
      const int rr1 = rem1 >> 2, q1 = rem1 & 3;
      int g1 = t0 - 2 + rr1;
      g1 = g1 < 0 ? 0 : (g1 > 127 ? 127 : g1);
      pf1 = *(const float4*)(x + ((size_t)(b0 + cb1) * 128 + g1) * 16 + q1 * 4);
    }
  }
  for (int cc = 0; cc < 4; cc++) {
    __syncthreads();  // previous compute done reading xs
    {
      const int cb = tid / 80, rem = tid % 80;
      const int rrow = rem >> 2, qq = rem & 3;
      *(float4*)(xs + cb * 400 + rrow * 20 + qq * 4) = pf0;
      if (tid < 64) {
        const int i2 = 256 + tid;
        const int cb1 = i2 / 80, rem1 = i2 % 80;
        const int rr1 = rem1 >> 2, q1 = rem1 & 3;
        *(float4*)(xs + cb1 * 400 + rr1 * 20 + q1 * 4) = pf1;
      }
    }
    __syncthreads();  // xs ready
    if (cc < 3) {  // prefetch next tile; lands before next ds_write
      const int bn = b0 + (cc + 1) * 4;
      const int cb = tid / 80, rem = tid % 80;
      const int rrow = rem >> 2, qq = rem & 3;
      int gr = t0 - 2 + rrow;
      gr = gr < 0 ? 0 : (gr > 127 ? 127 : gr);
      pf0 = *(const float4*)(x + ((size_t)(bn + cb) * 128 + gr) * 16 + qq * 4);
      if (tid < 64) {
        const int i2 = 256 + tid;
        const int cb1 = i2 / 80, rem1 = i2 % 80;
        const int rr1 = rem1 >> 2, q1 = rem1 & 3;
        int g1 = t0 - 2 + rr1;
        g1 = g1 < 0 ? 0 : (g1 > 127 ? 127 : g1);
        pf1 = *(const float4*)(x + ((size_t)(bn + cb1) * 128 + g1) * 16 + q1 * 4);
      }
    }
    #pragma unroll
    for (int cb = 0; cb < 4; cb++) {
      float acc0 = bo, acc1v = 0.f;
      #pragma unroll
      for (int dt = 0; dt < 5; dt++) {
        const float* xr = xs + cb * 400 + (tl + dt) * 20;
        const float4 xa = *(const float4*)(xr);
        const float4 xb = *(const float4*)(xr + 4);
        const float4 xc = *(const float4*)(xr + 8);
        const float4 xd = *(const float4*)(xr + 12);
        const float* Mp = M + dt * 16;
        acc0 += xa.x * Mp[0] + xa.y * Mp[1] + xa.z * Mp[2] + xa.w * Mp[3]
              + xb.x * Mp[4] + xb.y * Mp[5] + xb.z * Mp[6] + xb.w * Mp[7];
        acc1v += xc.x * Mp[8] + xc.y * Mp[9] + xc.z * Mp[10] + xc.w * Mp[11]
               + xd.x * Mp[12] + xd.y * Mp[13] + xd.z * Mp[14] + xd.w * Mp[15];
      }
      out[((size_t)(b0 + cc * 4 + cb) * 128 + t) * 16 + o] = acc0 + acc1v;
    }
  }
}

extern "C" void kernel_launch(void* const* d_in, const int* in_sizes, int n_in,
                              void* d_out, int out_size, void* d_ws, size_t ws_size,
                              hipStream_t stream) {
  const float* x    = (const float*)d_in[0];  // [1024,128,16]
  const float* W    = (const float*)d_in[1];  // [3,16,16]
  const float* bias = (const float*)d_in[2];  // [16]
  const float* adj  = (const float*)d_in[3];  // [16,16]
  (void)d_ws; (void)ws_size;                  // workspace deliberately UNUSED
  sgconv_fused<<<dim3(64, 8), dim3(256), 0, stream>>>(x, W, bias, adj, (float*)d_out);
}

// Round 4
// 84.355 us; speedup vs baseline: 12.3783x; 1.1313x over previous
//
#include <hip/hip_runtime.h>
#include <math.h>

// SGConv: out[b,t,o] = bias[o] + sum_k (x_flat @ cheb_k) @ W_k.
// R3 post-mortem: the two ~42us 256MiB ws-poison fills are UNCONDITIONAL
// (present with ws unused) => ~81us of every measurement is harness floor.
// Fusing sigma into the main kernel made all 512 blocks pay the ~25-barrier
// power-iteration chain (+11us). Revert to the proven R0 split:
//   kA_build (128 blocks): sigma + banded fused operator M -> ws (640KB, L2)
//   k3_main  (512 blocks): BW-bound apply, with R3's validated x-tile
//                          register prefetch grafted in (hides HBM latency).
// ws layout (floats): M[128][5][16][16] at 0 (163840 floats).

#define MU_MIN (-1.99940694f)   // -2*cos(pi/129)

__device__ __forceinline__ float dot16(float x) {  // sum over lanes 0..15
  x += __shfl_xor(x, 1);
  x += __shfl_xor(x, 2);
  x += __shfl_xor(x, 4);
  x += __shfl_xor(x, 8);
  return x;
}

// ---------------- Kernel A: sigma (power-squaring) + banded fused operator M ----------------
__global__ __launch_bounds__(256) void kA_build(const float* __restrict__ adj,
                                                const float* __restrict__ W,
                                                float* __restrict__ wsf) {
  const int t = blockIdx.x;
  const int tid = threadIdx.x;
  __shared__ float Bsh[256], Wsh[768];
  __shared__ float Dm[256], D0[256], Dp[256], DD[256];
  __shared__ float dis_i[16], dis_b[16], csh[1];
  __shared__ float H0[512], Pbuf[512], Qbuf[512];
  __shared__ float scl[2], lamsh[2];
  __shared__ int jst[2];

  {
    const int f = tid >> 4, g = tid & 15;
    const float a = adj[tid];
    const float s = 1.f / (1.f + expf(-a));
    Bsh[tid] = (f == g) ? 1.f : s;     // B = feat + self-loop (asymmetric)
    Wsh[tid] = W[tid];
    Wsh[tid + 256] = W[tid + 256];
    Wsh[tid + 512] = W[tid + 512];
  }
  __syncthreads();
  if (tid < 16) {
    float rsum = 0.f;
    for (int j = 0; j < 16; j++) rsum += Bsh[tid * 16 + j];  // row sums (d = sum axis=1)
    dis_i[tid] = 1.f / sqrtf(rsum + 2.f);  // interior t
    dis_b[tid] = 1.f / sqrtf(rsum + 1.f);  // t in {0,127}
  }
  __syncthreads();

  // --- sigma: both endpoint passes concurrently (thread halves) ---
  const int pass = tid >> 7, idx = tid & 127;
  const int pb = pass * 256;
  const float mu = pass ? -MU_MIN : MU_MIN;
  // G into Pbuf
  for (int e = idx; e < 256; e += 128) {
    const int f = e >> 4, g = e & 15;
    float gv = -dis_i[f] * Bsh[e] * dis_i[g];
    if (f == g) gv += 1.f - mu * dis_i[f] * dis_i[f];
    Pbuf[pb + e] = gv;
  }
  __syncthreads();
  // H0 = G^T G (symmetric PSD)
  for (int e = idx; e < 256; e += 128) {
    const int r = e >> 4, q = e & 15;
    float s = 0.f;
    #pragma unroll
    for (int k = 0; k < 16; k++) s += Pbuf[pb + k * 16 + r] * Pbuf[pb + k * 16 + q];
    H0[pb + e] = s;
    Qbuf[pb + e] = s;
  }
  __syncthreads();

  float* cur = Qbuf;
  float* nxt = Pbuf;
  #pragma unroll 1
  for (int it = 0; it < 8; it++) {   // cur -> cur^2 / trace^2   (H^256 total)
    if (idx == 0) {
      float tr = 0.f;
      #pragma unroll
      for (int d = 0; d < 16; d++) tr += cur[pb + d * 17];
      scl[pass] = 1.f / (tr * tr);
    }
    __syncthreads();
    const float s2 = scl[pass];
    for (int e = idx; e < 256; e += 128) {
      const int r = e >> 4, q = e & 15;
      const float4* rr = (const float4*)(cur + pb + r * 16);  // symmetric: col q = row q
      const float4* qq = (const float4*)(cur + pb + q * 16);
      float s = 0.f;
      #pragma unroll
      for (int k4 = 0; k4 < 4; k4++) {
        const float4 a = rr[k4], b = qq[k4];
        s += a.x * b.x + a.y * b.y + a.z * b.z + a.w * b.w;
      }
      nxt[pb + e] = s * s2;
    }
    __syncthreads();
    float* tmp = cur; cur = nxt; nxt = tmp;
  }
  if (idx == 0) {   // dominant column = argmax diagonal of H^256
    int bj = 0; float bd = -1.f;
    #pragma unroll
    for (int d = 0; d < 16; d++) {
      const float v = cur[pb + d * 17];
      if (v > bd) { bd = v; bj = d; }
    }
    jst[pass] = bj;
  }
  __syncthreads();
  if (idx < 16) {   // one-shot Rayleigh quotient of v = Hhat[:,j*] against H0
    const int r = idx, js = jst[pass];
    const float vr = cur[pb + r * 16 + js];
    float hv = 0.f;
    #pragma unroll
    for (int q = 0; q < 16; q++) hv += H0[pb + r * 16 + q] * cur[pb + q * 16 + js];
    const float num = dot16(vr * hv);
    const float den = dot16(vr * vr);
    if (r == 0) lamsh[pass] = num / fmaxf(den, 1e-30f);
  }
  __syncthreads();
  if (tid == 0) {
    const float lam = fmaxf(fmaxf(lamsh[0], lamsh[1]), 1e-20f);
    csh[0] = 2.f / sqrtf(lam);   // c = 2 / sigma
  }
  __syncthreads();

  const float c = csh[0];
  const int r = tid >> 4, q = tid & 15;

  auto uat = [&](int a_, int ff) -> float {
    return (a_ == 0 || a_ == 127) ? dis_b[ff] : dis_i[ff];
  };

  // Ls diagonal blocks: D_a[f,f'] = (c-1) delta - c u_a(f) u_a(f') B[f,f']
  D0[tid] = ((r == q) ? (c - 1.f) : 0.f) - c * uat(t, r) * uat(t, q) * Bsh[tid];
  if (t > 0)   Dm[tid] = ((r == q) ? (c - 1.f) : 0.f) - c * uat(t - 1, r) * uat(t - 1, q) * Bsh[tid];
  if (t < 127) Dp[tid] = ((r == q) ? (c - 1.f) : 0.f) - c * uat(t + 1, r) * uat(t + 1, q) * Bsh[tid];
  __syncthreads();
  {
    float s = 0.f;
    #pragma unroll
    for (int k = 0; k < 16; k++) s += D0[r * 16 + k] * D0[k * 16 + q];
    DD[tid] = s;  // D_t^2
  }
  __syncthreads();

  const int fo = r;   // input feature f (row of P block at time t+dt)
  const int o = q;    // output channel
  float m[5];
  const float ut_f = uat(t, fo);

  // dt = 0:  W0 + D_t W1 + (2 D_t^2 + diag(2 c^2 u_t^2 (u_{t-1}^2 + u_{t+1}^2)) - I) W2
  {
    float acc = Wsh[fo * 16 + o];
    const float diag0 = 2.f * c * c * ut_f * ut_f *
                        ((t > 0 ? uat(t - 1, fo) * uat(t - 1, fo) : 0.f) +
                         (t < 127 ? uat(t + 1, fo) * uat(t + 1, fo) : 0.f)) - 1.f;
    #pragma unroll
    for (int fp = 0; fp < 16; fp++) {
      acc += D0[fo * 16 + fp] * Wsh[256 + fp * 16 + o];
      const float p2 = 2.f * DD[fo * 16 + fp] + ((fo == fp) ? diag0 : 0.f);
      acc += p2 * Wsh[512 + fp * 16 + o];
    }
    m[2] = acc;
  }
  // dt = +1: P1 = diag(g), P2 = 2(g(f) D_t + D_{t+1} g(f')),  g = -c u_{t+1} u_t
  if (t < 127) {
    const float gf = -c * uat(t + 1, fo) * ut_f;
    float acc = gf * Wsh[256 + fo * 16 + o];
    #pragma unroll
    for (int fp = 0; fp < 16; fp++) {
      const float gq = -c * uat(t + 1, fp) * uat(t, fp);
      const float p2 = 2.f * (gf * D0[fo * 16 + fp] + Dp[fo * 16 + fp] * gq);
      acc += p2 * Wsh[512 + fp * 16 + o];
    }
    m[3] = acc;
  } else m[3] = 0.f;
  // dt = -1
  if (t > 0) {
    const float gf = -c * uat(t - 1, fo) * ut_f;
    float acc = gf * Wsh[256 + fo * 16 + o];
    #pragma unroll
    for (int fp = 0; fp < 16; fp++) {
      const float gq = -c * uat(t - 1, fp) * uat(t, fp);
      const float p2 = 2.f * (Dm[fo * 16 + fp] * gq + gf * D0[fo * 16 + fp]);
      acc += p2 * Wsh[512 + fp * 16 + o];
    }
    m[1] = acc;
  } else m[1] = 0.f;
  // dt = +/-2: diagonal 2 c^2 u_{t+-2} u_{t+-1}^2 u_t
  m[4] = (t < 126) ? (2.f * c * c * uat(t + 2, fo) * uat(t + 1, fo) * uat(t + 1, fo) * ut_f
                      * Wsh[512 + fo * 16 + o]) : 0.f;
  m[0] = (t > 1) ? (2.f * c * c * uat(t - 2, fo) * uat(t - 1, fo) * uat(t - 1, fo) * ut_f
                    * Wsh[512 + fo * 16 + o]) : 0.f;

  #pragma unroll
  for (int d5 = 0; d5 < 5; d5++)
    wsf[((size_t)(t * 5 + d5) * 16 + fo) * 16 + o] = m[d5];
}

// ---------------- Kernel 3: out[b,t,o] = bias + sum_{dt,f} x[b,t+dt,f] M[t][dt][f][o] ----
__global__ __launch_bounds__(256) void k3_main(const float* __restrict__ x,
                                               const float* __restrict__ bias,
                                               const float* __restrict__ wsf,
                                               float* __restrict__ out) {
  const int tg = blockIdx.y, bg = blockIdx.x;
  const int t0 = tg * 16, b0 = bg * 16;
  const int tid = threadIdx.x;
  const int tl = tid >> 4, o = tid & 15;
  const int t = t0 + tl;

  float M[80];  // M column for this (t,o): [dt][f]
  {
    const float* Mt = wsf + (size_t)t * 5 * 256;
    #pragma unroll
    for (int i = 0; i < 80; i++) M[i] = Mt[i * 16 + o];
  }
  const float bo = bias[o];

  __shared__ float xs[1600];  // 4 batches x 20 rows x (16+4 pad) floats

  // register prefetch of tile cc=0 (R3-validated pattern: 256 + 64 float4s)
  float4 pf0, pf1;
  {
    const int cb = tid / 80, rem = tid % 80;
    const int rrow = rem >> 2, qq = rem & 3;
    int gr = t0 - 2 + rrow;
    gr = gr < 0 ? 0 : (gr > 127 ? 127 : gr);  // clamped rows hit M==0 entries
    pf0 = *(const float4*)(x + ((size_t)(b0 + cb) * 128 + gr) * 16 + qq * 4);
    if (tid < 64) {
      const int i2 = 256 + tid;
      const int cb1 = i2 / 80, rem1 = i2 % 80;
      const int rr1 = rem1 >> 2, q1 = rem1 & 3;
      int g1 = t0 - 2 + rr1;
      g1 = g1 < 0 ? 0 : (g1 > 127 ? 127 : g1);
      pf1 = *(const float4*)(x + ((size_t)(b0 + cb1) * 128 + g1) * 16 + q1 * 4);
    }
  }

  for (int cc = 0; cc < 4; cc++) {
    __syncthreads();  // previous compute done reading xs
    {
      const int cb = tid / 80, rem = tid % 80;
      const int rrow = rem >> 2, qq = rem & 3;
      *(float4*)(xs + cb * 400 + rrow * 20 + qq * 4) = pf0;
      if (tid < 64) {
        const int i2 = 256 + tid;
        const int cb1 = i2 / 80, rem1 = i2 % 80;
        const int rr1 = rem1 >> 2, q1 = rem1 & 3;
        *(float4*)(xs + cb1 * 400 + rr1 * 20 + q1 * 4) = pf1;
      }
    }
    __syncthreads();  // xs ready
    if (cc < 3) {  // prefetch next tile; lands before next ds_write
      const int bn = b0 + (cc + 1) * 4;
      const int cb = tid / 80, rem = tid % 80;
      const int rrow = rem >> 2, qq = rem & 3;
      int gr = t0 - 2 + rrow;
      gr = gr < 0 ? 0 : (gr > 127 ? 127 : gr);
      pf0 = *(const float4*)(x + ((size_t)(bn + cb) * 128 + gr) * 16 + qq * 4);
      if (tid < 64) {
        const int i2 = 256 + tid;
        const int cb1 = i2 / 80, rem1 = i2 % 80;
        const int rr1 = rem1 >> 2, q1 = rem1 & 3;
        int g1 = t0 - 2 + rr1;
        g1 = g1 < 0 ? 0 : (g1 > 127 ? 127 : g1);
        pf1 = *(const float4*)(x + ((size_t)(bn + cb1) * 128 + g1) * 16 + q1 * 4);
      }
    }
    #pragma unroll
    for (int cb = 0; cb < 4; cb++) {
      float acc0 = bo, acc1v = 0.f;
      #pragma unroll
      for (int dt = 0; dt < 5; dt++) {
        const float* xr = xs + cb * 400 + (tl + dt) * 20;
        const float4 xa = *(const float4*)(xr);
        const float4 xb = *(const float4*)(xr + 4);
        const float4 xc = *(const float4*)(xr + 8);
        const float4 xd = *(const float4*)(xr + 12);
        const float* Mp = M + dt * 16;
        acc0 += xa.x * Mp[0] + xa.y * Mp[1] + xa.z * Mp[2] + xa.w * Mp[3]
              + xb.x * Mp[4] + xb.y * Mp[5] + xb.z * Mp[6] + xb.w * Mp[7];
        acc1v += xc.x * Mp[8] + xc.y * Mp[9] + xc.z * Mp[10] + xc.w * Mp[11]
               + xd.x * Mp[12] + xd.y * Mp[13] + xd.z * Mp[14] + xd.w * Mp[15];
      }
      out[((size_t)(b0 + cc * 4 + cb) * 128 + t) * 16 + o] = acc0 + acc1v;
    }
  }
}

extern "C" void kernel_launch(void* const* d_in, const int* in_sizes, int n_in,
                              void* d_out, int out_size, void* d_ws, size_t ws_size,
                              hipStream_t stream) {
  const float* x    = (const float*)d_in[0];  // [1024,128,16]
  const float* W    = (const float*)d_in[1];  // [3,16,16]
  const float* bias = (const float*)d_in[2];  // [16]
  const float* adj  = (const float*)d_in[3];  // [16,16]
  float* out = (float*)d_out;
  float* wsf = (float*)d_ws;  // needs 163840 floats (~656 KB)

  kA_build<<<dim3(128), dim3(256), 0, stream>>>(adj, W, wsf);
  k3_main<<<dim3(64, 8), dim3(256), 0, stream>>>(x, bias, wsf, out);
}